// Round 11
// baseline (1713.093 us; speedup 1.0000x reference)
//
#include <hip/hip_runtime.h>
#include <math.h>

#define NNODES 50000
#define NEDGE  800000
#define NG     3
#define GE     (NG*NEDGE)            // 2,400,000 combined edges
#define NBUK   2048                  // row buckets: bucket(r) = r*128/3125 -> 24/25 rows each
#define OS     (NBUK + 1)            // 2049, off1 row stride
#define CH     9375                  // edges per bin job; 256*9375 == GE exactly
#define NBLK   256                   // bin jobs
#define GBLK   391                   // gemm jobs of 128 rows (391*128 = 50048)
#define FGRID  (GBLK + NBLK)         // 647 fused front blocks

typedef __attribute__((ext_vector_type(8))) short bf16x8;
typedef __attribute__((ext_vector_type(4))) float f32x4;

// fp32 -> bf16 round-to-nearest-even (no NaN inputs here)
__device__ __forceinline__ unsigned short f2bf(float f) {
    unsigned u = __float_as_uint(f);
    return (unsigned short)((u + 0x7fffu + ((u >> 16) & 1u)) >> 16);
}

// bucket of row r: floor(r*2048/50000) = floor(r*128/3125); exact for r < 50000
__device__ __forceinline__ int bucket_of(unsigned r) {
    return (int)((r * 128u) / 3125u);
}

// ---------------------------------------------------------------------------
// K_FRONT: byte-identical to r8 (proven; ledger says ~42us).
// ---------------------------------------------------------------------------
__global__ __launch_bounds__(512) void k_front(const float* __restrict__ X,
                                               const float* __restrict__ W,
                                               const int* __restrict__ rows,
                                               const int* __restrict__ cols,
                                               const float* __restrict__ vals,
                                               const float* __restrict__ alpha,
                                               unsigned short* __restrict__ hb16,
                                               uint2* __restrict__ out1,
                                               unsigned short* __restrict__ off1) {
    __shared__ __align__(16) char smem[34816];
    const int t = threadIdx.x;

    if (blockIdx.x < GBLK) {
        // ---------------- GEMM path ----------------
        uint4* Wl = (uint4*)smem;   // 2048 records = 32KB, MFMA B-fragment order
        for (int i = t; i < 2048; i += 512) {
            const int nt   = i >> 8;
            const int kc   = (i >> 6) & 3;
            const int lane = i & 63;
            const int n  = nt * 16 + (lane & 15);
            const int k0 = kc * 32 + (lane >> 4) * 8;
            const float* src = W + (size_t)n * 128 + k0;
            float4 a = *(const float4*)(src);
            float4 b = *(const float4*)(src + 4);
            unsigned u0 = (unsigned)f2bf(a.x) | ((unsigned)f2bf(a.y) << 16);
            unsigned u1 = (unsigned)f2bf(a.z) | ((unsigned)f2bf(a.w) << 16);
            unsigned u2 = (unsigned)f2bf(b.x) | ((unsigned)f2bf(b.y) << 16);
            unsigned u3 = (unsigned)f2bf(b.z) | ((unsigned)f2bf(b.w) << 16);
            Wl[i] = make_uint4(u0, u1, u2, u3);
        }
        __syncthreads();

        const int w    = t >> 6;
        const int lane = t & 63;
        const int q    = lane >> 4;
        const int ml   = lane & 15;
        const int m0   = blockIdx.x * 128 + w * 16;

        int xr = m0 + ml; if (xr >= NNODES) xr = NNODES - 1;   // clamp (stores guarded)
        const float* xrow = X + (size_t)xr * 128;

        bf16x8 xf[4];
#pragma unroll
        for (int kc = 0; kc < 4; ++kc) {
            const int k0 = kc * 32 + q * 8;
            float4 a = *(const float4*)(xrow + k0);
            float4 b = *(const float4*)(xrow + k0 + 4);
            bf16x8 v;
            v[0] = (short)f2bf(a.x); v[1] = (short)f2bf(a.y);
            v[2] = (short)f2bf(a.z); v[3] = (short)f2bf(a.w);
            v[4] = (short)f2bf(b.x); v[5] = (short)f2bf(b.y);
            v[6] = (short)f2bf(b.z); v[7] = (short)f2bf(b.w);
            xf[kc] = v;
        }

        f32x4 acc[8];
#pragma unroll
        for (int nt = 0; nt < 8; ++nt) acc[nt] = (f32x4){0.f, 0.f, 0.f, 0.f};
#pragma unroll
        for (int nt = 0; nt < 8; ++nt)
#pragma unroll
            for (int kc = 0; kc < 4; ++kc) {
                const bf16x8 wf = *(const bf16x8*)&Wl[(nt * 4 + kc) * 64 + lane];
                acc[nt] = __builtin_amdgcn_mfma_f32_16x16x32_bf16(xf[kc], wf, acc[nt], 0, 0, 0);
            }
        __syncthreads();   // done reading Wl; reuse region for transpose

        unsigned short* hst = (unsigned short*)smem + w * 2176;
#pragma unroll
        for (int nt = 0; nt < 8; ++nt)
#pragma unroll
            for (int r = 0; r < 4; ++r)
                hst[(q * 4 + r) * 136 + nt * 16 + ml] = f2bf(acc[nt][r]);
        __syncthreads();

#pragma unroll
        for (int i = 0; i < 4; ++i) {
            const int chunk = i * 64 + lane;
            const int lr    = chunk >> 4;
            const int cc    = chunk & 15;
            const int row   = m0 + lr;
            const uint4 v = *(const uint4*)(hst + lr * 136 + cc * 8);
            if (row < NNODES)
                ((uint4*)(hb16 + (size_t)row * 128))[cc] = v;
        }
    } else {
        // ---------------- BIN path (CH=9375, 26.9KB LDS) ----------------
        unsigned short* rnk = (unsigned short*)smem;         // 18,750 B
        int*            sA  = (int*)(smem + 18752);          //  8,192 B
        const int bb    = blockIdx.x - GBLK;
        const int start = bb * CH;                           // end = start+CH (exact fit)

        const float g0 = 1.0f / (1.0f + __expf(-alpha[0]));
        const float g1 = 1.0f / (1.0f + __expf(-alpha[1]));
        const float g2 = 1.0f / (1.0f + __expf(-alpha[2]));

#pragma unroll
        for (int j = 0; j < 4; ++j) sA[t + j * 512] = 0;
        __syncthreads();

        // pass 1: histogram + rank (rows stream only)
        for (int k = t; k < CH; k += 512) {
            const int r = rows[start + k];
            rnk[k] = (unsigned short)atomicAdd(&sA[bucket_of((unsigned)r)], 1);
        }
        __syncthreads();

        // in-place inclusive scan over 2048 (11 steps)
        for (int off = 1; off < 2048; off <<= 1) {
            int v[4];
#pragma unroll
            for (int j = 0; j < 4; ++j) {
                const int i = t + j * 512;
                v[j] = sA[i] + ((i >= off) ? sA[i - off] : 0);
            }
            __syncthreads();
#pragma unroll
            for (int j = 0; j < 4; ++j) sA[t + j * 512] = v[j];
            __syncthreads();
        }

        // off1 = exclusive offsets (values <= 9375 -> u16)
        for (int b = t; b < NBUK; b += 512)
            off1[(size_t)bb * OS + b] = (unsigned short)(b ? sA[b - 1] : 0);
        if (t == 0) off1[(size_t)bb * OS + NBUK] = (unsigned short)sA[NBUK - 1];

        // pass 2: re-read edge streams (contiguous, L2-hot), scatter to out1
        for (int k = t; k < CH; k += 512) {
            const int idx = start + k;
            const int r = rows[idx];
            const int c = cols[idx];
            const float v = vals[idx];
            const float gv = v * (idx < NEDGE ? g0 : (idx < 2 * NEDGE ? g1 : g2));
            const int b = bucket_of((unsigned)r);
            const int pos = (b ? sA[b - 1] : 0) + (int)rnk[k];
            uint2 rec;
            rec.x = ((unsigned)r << 16) | (unsigned)c;
            rec.y = __float_as_uint(gv);
            out1[(size_t)bb * CH + pos] = rec;
        }
    }
}

// ---------------------------------------------------------------------------
// K_AGG r11: sort machinery DELETED (it was ~2/3 of agg's VALU; the phase
// windows it enabled were worth only 3.6us, r4). Per bucket: zero a 25x128
// f32 LDS accumulator, then each wave walks its share of the 256 segments;
// per edge: wave-uniform record -> readfirstlane puts row/col/addr on the
// SCALAR pipe; gather hbits row (saddr + lane offset); ds_add_f32 into
// accL[row][2*lane..+1]. No scans, no stg, no rank atomics, 3 barriers total.
// 256-thr blocks, LDS 12.8KB -> 8 blocks/CU, 2048 blocks = EXACTLY one pass.
// ---------------------------------------------------------------------------
__global__ __launch_bounds__(256, 8) void k_agg(const unsigned* __restrict__ hbits,
                                                const uint2* __restrict__ out1,
                                                const unsigned short* __restrict__ off1,
                                                float* __restrict__ out) {
    __shared__ float accL[25 * 128];           // 12,800 B
    const int t    = threadIdx.x;
    const int b    = blockIdx.x;
    const int lane = t & 63;
    const int wid  = t >> 6;                   // 4 waves

    // bucket row range: [ceil(b*3125/128), ceil((b+1)*3125/128))
    const int sstart = (b * 3125 + 127) >> 7;
    const int send   = ((b + 1) * 3125 + 127) >> 7;
    const int width  = send - sstart;          // 24 or 25

    for (int i = t; i < width * 128; i += 256) accL[i] = 0.f;
    __syncthreads();

    // wave wid walks segments wid, wid+4, ... (64 segments per wave)
    for (int sg = wid; sg < NBLK; sg += 4) {
        const int s0 = off1[(size_t)sg * OS + b];
        const int e0 = off1[(size_t)sg * OS + b + 1];
        const uint2* segp = out1 + (size_t)sg * CH;
        int i = s0;
        for (; i + 2 <= e0; i += 2) {
            const uint2 r0 = segp[i];
            const uint2 r1 = segp[i + 1];
            const unsigned x0 = __builtin_amdgcn_readfirstlane(r0.x);
            const float    v0 = __uint_as_float(__builtin_amdgcn_readfirstlane(r0.y));
            const unsigned x1 = __builtin_amdgcn_readfirstlane(r1.x);
            const float    v1 = __uint_as_float(__builtin_amdgcn_readfirstlane(r1.y));
            const unsigned h0 = hbits[((x0 & 0xffffu) << 6) | (unsigned)lane];
            const unsigned h1 = hbits[((x1 & 0xffffu) << 6) | (unsigned)lane];
            float* a0 = accL + ((int)(x0 >> 16) - sstart) * 128 + 2 * lane;
            float* a1 = accL + ((int)(x1 >> 16) - sstart) * 128 + 2 * lane;
            unsafeAtomicAdd(a0,     v0 * __uint_as_float(h0 << 16));
            unsafeAtomicAdd(a0 + 1, v0 * __uint_as_float(h0 & 0xffff0000u));
            unsafeAtomicAdd(a1,     v1 * __uint_as_float(h1 << 16));
            unsafeAtomicAdd(a1 + 1, v1 * __uint_as_float(h1 & 0xffff0000u));
        }
        if (i < e0) {
            const uint2 r0 = segp[i];
            const unsigned x0 = __builtin_amdgcn_readfirstlane(r0.x);
            const float    v0 = __uint_as_float(__builtin_amdgcn_readfirstlane(r0.y));
            const unsigned h0 = hbits[((x0 & 0xffffu) << 6) | (unsigned)lane];
            float* a0 = accL + ((int)(x0 >> 16) - sstart) * 128 + 2 * lane;
            unsafeAtomicAdd(a0,     v0 * __uint_as_float(h0 << 16));
            unsafeAtomicAdd(a0 + 1, v0 * __uint_as_float(h0 & 0xffff0000u));
        }
    }
    __syncthreads();

    // store: accL is exactly out[sstart*128 .. send*128) -- fully linear
    float4*       d4 = (float4*)(out + (size_t)sstart * 128);
    const float4* s4 = (const float4*)accL;
    for (int i = t; i < width * 32; i += 256) d4[i] = s4[i];
}

extern "C" void kernel_launch(void* const* d_in, const int* in_sizes, int n_in,
                              void* d_out, int out_size, void* d_ws, size_t ws_size,
                              hipStream_t stream) {
    const float* X     = (const float*)d_in[0];
    const float* W     = (const float*)d_in[1];
    const float* alpha = (const float*)d_in[2];
    const int*   rows  = (const int*)d_in[3];
    const int*   cols  = (const int*)d_in[4];
    const float* vals  = (const float*)d_in[5];
    float* out = (float*)d_out;

    // workspace layout (33,049,088 B <= proven 33,870,176 footprint)
    char* ws = (char*)d_ws;
    unsigned*       hbits = (unsigned*)(ws + 0);              // 12,800,000 B
    unsigned short* hb16  = (unsigned short*)(ws + 0);        // same bytes, u16 view
    uint2*          out1  = (uint2*)(ws + 12800000);          // 256*9375*8 = 19,200,000 B
    unsigned short* off1  = (unsigned short*)(ws + 32000000); // 256*2049*2 =  1,049,088 B

    hipLaunchKernelGGL(k_front, dim3(FGRID), dim3(512), 0, stream,
                       X, W, rows, cols, vals, alpha, hb16, out1, off1);
    hipLaunchKernelGGL(k_agg, dim3(NBUK), dim3(256), 0, stream,
                       hbits, out1, off1, out);
}